// Round 1
// baseline (3605.967 us; speedup 1.0000x reference)
//
#include <hip/hip_runtime.h>
#include <hip/hip_bf16.h>

#define NN 50000
#define NE 600000
#define FD 128
#define NG 512
#define NC 10
static constexpr float EPS_BN = 1e-5f;

// ---------------- degree / norm ----------------
__global__ __launch_bounds__(256) void k_init_deg(float* __restrict__ deg) {
  int i = blockIdx.x * 256 + threadIdx.x;
  if (i < NN) deg[i] = 1.0f;   // self-loop
}

__global__ __launch_bounds__(256) void k_deg_scatter(const int* __restrict__ dst, float* __restrict__ deg) {
  int e = blockIdx.x * 256 + threadIdx.x;
  if (e < NE) unsafeAtomicAdd(&deg[dst[e]], 1.0f);
}

__global__ __launch_bounds__(256) void k_rsqrt(float* __restrict__ deg) {
  int i = blockIdx.x * 256 + threadIdx.x;
  if (i < NN) deg[i] = rsqrtf(deg[i]);   // deg >= 1 always
}

// ---------------- dense GEMM: out[r][c] = sum_k in[r][k] * W[c][k] ----------------
#define GEMM_ROWS 32
__global__ __launch_bounds__(256) void k_gemm(const float* __restrict__ in, const float* __restrict__ W,
                                              float* __restrict__ out) {
  __shared__ float wl[FD][FD + 1];          // 66KB, pad -> conflict-free col reads
  __shared__ float xl[GEMM_ROWS][FD + 1];   // 16.5KB
  int t = threadIdx.x;
  int row0 = blockIdx.x * GEMM_ROWS;
  for (int i = t; i < FD * FD; i += 256) wl[i >> 7][i & 127] = W[i];
  for (int i = t; i < GEMM_ROWS * FD; i += 256) {
    int r = i >> 7, c = i & 127;
    int gr = row0 + r;
    xl[r][c] = (gr < NN) ? in[gr * FD + c] : 0.0f;
  }
  __syncthreads();
  int tr = (t >> 5) << 2;   // 8 row-groups of 4
  int tc = t & 31;          // cols tc + 32j
  float acc[4][4];
#pragma unroll
  for (int i = 0; i < 4; ++i)
#pragma unroll
    for (int j = 0; j < 4; ++j) acc[i][j] = 0.0f;

#pragma unroll 8
  for (int k = 0; k < FD; ++k) {
    float a0 = xl[tr + 0][k], a1 = xl[tr + 1][k], a2 = xl[tr + 2][k], a3 = xl[tr + 3][k];
    float b0 = wl[tc][k], b1 = wl[tc + 32][k], b2 = wl[tc + 64][k], b3 = wl[tc + 96][k];
    acc[0][0] = fmaf(a0, b0, acc[0][0]); acc[0][1] = fmaf(a0, b1, acc[0][1]);
    acc[0][2] = fmaf(a0, b2, acc[0][2]); acc[0][3] = fmaf(a0, b3, acc[0][3]);
    acc[1][0] = fmaf(a1, b0, acc[1][0]); acc[1][1] = fmaf(a1, b1, acc[1][1]);
    acc[1][2] = fmaf(a1, b2, acc[1][2]); acc[1][3] = fmaf(a1, b3, acc[1][3]);
    acc[2][0] = fmaf(a2, b0, acc[2][0]); acc[2][1] = fmaf(a2, b1, acc[2][1]);
    acc[2][2] = fmaf(a2, b2, acc[2][2]); acc[2][3] = fmaf(a2, b3, acc[2][3]);
    acc[3][0] = fmaf(a3, b0, acc[3][0]); acc[3][1] = fmaf(a3, b1, acc[3][1]);
    acc[3][2] = fmaf(a3, b2, acc[3][2]); acc[3][3] = fmaf(a3, b3, acc[3][3]);
  }
#pragma unroll
  for (int i = 0; i < 4; ++i) {
    int r = row0 + tr + i;
    if (r < NN) {
      out[r * FD + tc]      = acc[i][0];
      out[r * FD + tc + 32] = acc[i][1];
      out[r * FD + tc + 64] = acc[i][2];
      out[r * FD + tc + 96] = acc[i][3];
    }
  }
}

// ---------------- aggregation ----------------
// out[n] = bias + dinv[n]^2 * h[n]   (self-loop + bias)
__global__ __launch_bounds__(256) void k_agg_init(const float* __restrict__ h, const float* __restrict__ dinv,
                                                  const float* __restrict__ bias, float* __restrict__ out) {
  int i = blockIdx.x * 256 + threadIdx.x;     // float4 index over NN*FD/4
  if (i >= NN * FD / 4) return;
  int n = i >> 5, q = i & 31;
  float dv = dinv[n];
  float s = dv * dv;
  float4 hv = ((const float4*)h)[i];
  float4 bv = ((const float4*)bias)[q];
  float4 o;
  o.x = bv.x + s * hv.x;
  o.y = bv.y + s * hv.y;
  o.z = bv.z + s * hv.z;
  o.w = bv.w + s * hv.w;
  ((float4*)out)[i] = o;
}

// out[dst] += dinv[src]*dinv[dst] * h[src]   32 lanes/edge, float4 each
__global__ __launch_bounds__(256) void k_agg_scatter(const int* __restrict__ src, const int* __restrict__ dst,
                                                     const float* __restrict__ dinv, const float* __restrict__ h,
                                                     float* __restrict__ out) {
  int i = blockIdx.x * 256 + threadIdx.x;
  if (i >= NE * 32) return;
  int e = i >> 5, q = i & 31;
  int s = src[e], d = dst[e];
  float nrm = dinv[s] * dinv[d];
  float4 hv = ((const float4*)h)[s * 32 + q];
  float* op = out + (size_t)d * FD + q * 4;
  unsafeAtomicAdd(op + 0, nrm * hv.x);
  unsafeAtomicAdd(op + 1, nrm * hv.y);
  unsafeAtomicAdd(op + 2, nrm * hv.z);
  unsafeAtomicAdd(op + 3, nrm * hv.w);
}

// ---------------- batchnorm ----------------
#define BN_BLOCKS 512
#define BN_RPB 98   // 512*98 = 50176 >= 50000
__global__ __launch_bounds__(256) void k_bn_stats(const float* __restrict__ h, float* __restrict__ bnsum,
                                                  float* __restrict__ bnsq) {
  int t = threadIdx.x;
  int f = t & 127;
  int half = t >> 7;
  int r0 = blockIdx.x * BN_RPB + half;
  int r1 = min((int)(blockIdx.x + 1) * BN_RPB, NN);
  float s = 0.f, q = 0.f;
  for (int r = r0; r < r1; r += 2) {
    float v = h[r * FD + f];
    s += v;
    q += v * v;
  }
  unsafeAtomicAdd(&bnsum[f], s);
  unsafeAtomicAdd(&bnsq[f], q);
}

__global__ __launch_bounds__(128) void k_bn_final(const float* __restrict__ bnsum, const float* __restrict__ bnsq,
                                                  float* __restrict__ mu, float* __restrict__ scale) {
  int f = threadIdx.x;
  if (f < FD) {
    float m = bnsum[f] * (1.0f / NN);
    float v = bnsq[f] * (1.0f / NN) - m * m;
    v = fmaxf(v, 0.0f);
    mu[f] = m;
    scale[f] = rsqrtf(v + EPS_BN);
  }
}

__global__ __launch_bounds__(256) void k_bn_apply(float* __restrict__ h, const float* __restrict__ mu,
                                                  const float* __restrict__ scale) {
  int i = blockIdx.x * 256 + threadIdx.x;
  if (i >= NN * FD / 4) return;
  int q = i & 31;
  float4 v = ((float4*)h)[i];
  float4 m = ((const float4*)mu)[q];
  float4 sc = ((const float4*)scale)[q];
  v.x = fmaxf((v.x - m.x) * sc.x, 0.0f);
  v.y = fmaxf((v.y - m.y) * sc.y, 0.0f);
  v.z = fmaxf((v.z - m.z) * sc.z, 0.0f);
  v.w = fmaxf((v.w - m.w) * sc.w, 0.0f);
  ((float4*)h)[i] = v;
}

// ---------------- pooling + head ----------------
__global__ __launch_bounds__(256) void k_pool(const float* __restrict__ h, const int* __restrict__ batch,
                                              float* __restrict__ pooled) {
  int i = blockIdx.x * 256 + threadIdx.x;
  if (i >= NN * 32) return;
  int n = i >> 5, q = i & 31;
  int g = batch[n];
  float4 v = ((const float4*)h)[i];
  float* pp = pooled + g * FD + q * 4;
  unsafeAtomicAdd(pp + 0, v.x);
  unsafeAtomicAdd(pp + 1, v.y);
  unsafeAtomicAdd(pp + 2, v.z);
  unsafeAtomicAdd(pp + 3, v.w);
}

__global__ __launch_bounds__(256) void k_cnt(const int* __restrict__ batch, float* __restrict__ cnt) {
  int n = blockIdx.x * 256 + threadIdx.x;
  if (n < NN) unsafeAtomicAdd(&cnt[batch[n]], 1.0f);
}

__global__ __launch_bounds__(128) void k_final(const float* __restrict__ pooled, const float* __restrict__ cnt,
                                               const float* __restrict__ Wlin, const float* __restrict__ blin,
                                               float* __restrict__ out) {
  __shared__ float p[FD];
  int g = blockIdx.x, t = threadIdx.x;
  float ic = 1.0f / fmaxf(cnt[g], 1.0f);
  p[t] = pooled[g * FD + t] * ic;
  __syncthreads();
  if (t < NC) {
    float a = blin[t];
    for (int k = 0; k < FD; ++k) a = fmaf(p[k], Wlin[t * FD + k], a);
    out[g * NC + t] = a;
  }
}

// ---------------- launch ----------------
extern "C" void kernel_launch(void* const* d_in, const int* in_sizes, int n_in,
                              void* d_out, int out_size, void* d_ws, size_t ws_size,
                              hipStream_t stream) {
  const float* x    = (const float*)d_in[0];
  const int*   ei   = (const int*)d_in[1];
  const int*   batch= (const int*)d_in[2];
  const float* W1   = (const float*)d_in[3];
  const float* b1   = (const float*)d_in[4];
  const float* W2   = (const float*)d_in[5];
  const float* b2   = (const float*)d_in[6];
  const float* W3   = (const float*)d_in[7];
  const float* b3   = (const float*)d_in[8];
  const float* Wlin = (const float*)d_in[9];
  const float* blin = (const float*)d_in[10];
  float* out = (float*)d_out;
  float* ws  = (float*)d_ws;

  const int* srcI = ei;
  const int* dstI = ei + NE;

  float* deg    = ws;                    // NN (holds dinv after k_rsqrt)
  float* bufA   = ws + 50048;            // NN*FD
  float* bufB   = bufA + NN * FD;        // NN*FD
  float* bnsum  = bufB + NN * FD;        // FD
  float* bnsq   = bnsum + FD;            // FD
  float* mu     = bnsq + FD;             // FD
  float* scale  = mu + FD;               // FD
  float* pooled = scale + FD;            // NG*FD
  float* cnt    = pooled + NG * FD;      // NG

  dim3 B(256);
  const int gN    = (NN + 255) / 256;
  const int gE    = (NE + 255) / 256;
  const int gGemm = (NN + GEMM_ROWS - 1) / GEMM_ROWS;
  const int gEl4  = (NN * FD / 4 + 255) / 256;
  const int gScat = (NE * 32 + 255) / 256;

  // degree -> dinv
  k_init_deg<<<gN, B, 0, stream>>>(deg);
  k_deg_scatter<<<gE, B, 0, stream>>>(dstI, deg);
  k_rsqrt<<<gN, B, 0, stream>>>(deg);

  // layer 1
  k_gemm<<<gGemm, B, 0, stream>>>(x, W1, bufA);
  k_agg_init<<<gEl4, B, 0, stream>>>(bufA, deg, b1, bufB);
  k_agg_scatter<<<gScat, B, 0, stream>>>(srcI, dstI, deg, bufA, bufB);
  hipMemsetAsync(bnsum, 0, 2 * FD * sizeof(float), stream);
  k_bn_stats<<<BN_BLOCKS, B, 0, stream>>>(bufB, bnsum, bnsq);
  k_bn_final<<<1, 128, 0, stream>>>(bnsum, bnsq, mu, scale);
  k_bn_apply<<<gEl4, B, 0, stream>>>(bufB, mu, scale);

  // layer 2
  k_gemm<<<gGemm, B, 0, stream>>>(bufB, W2, bufA);
  k_agg_init<<<gEl4, B, 0, stream>>>(bufA, deg, b2, bufB);
  k_agg_scatter<<<gScat, B, 0, stream>>>(srcI, dstI, deg, bufA, bufB);
  hipMemsetAsync(bnsum, 0, 2 * FD * sizeof(float), stream);
  k_bn_stats<<<BN_BLOCKS, B, 0, stream>>>(bufB, bnsum, bnsq);
  k_bn_final<<<1, 128, 0, stream>>>(bnsum, bnsq, mu, scale);
  k_bn_apply<<<gEl4, B, 0, stream>>>(bufB, mu, scale);

  // layer 3 (no BN/ReLU)
  k_gemm<<<gGemm, B, 0, stream>>>(bufB, W3, bufA);
  k_agg_init<<<gEl4, B, 0, stream>>>(bufA, deg, b3, bufB);
  k_agg_scatter<<<gScat, B, 0, stream>>>(srcI, dstI, deg, bufA, bufB);

  // pool + head
  hipMemsetAsync(pooled, 0, (NG * FD + NG) * sizeof(float), stream);
  k_pool<<<(NN * 32 + 255) / 256, B, 0, stream>>>(bufB, batch, pooled);
  k_cnt<<<gN, B, 0, stream>>>(batch, cnt);
  k_final<<<NG, 128, 0, stream>>>(pooled, cnt, Wlin, blin, out);
}

// Round 2
// 748.248 us; speedup vs baseline: 4.8192x; 4.8192x over previous
//
#include <hip/hip_runtime.h>
#include <hip/hip_bf16.h>

#define NN 50000
#define NE 600000
#define FD 128
#define NG 512
#define NC 10
static constexpr float EPS_BN = 1e-5f;

// ---------------- degree / norm ----------------
__global__ __launch_bounds__(256) void k_init_deg(float* __restrict__ deg) {
  int i = blockIdx.x * 256 + threadIdx.x;
  if (i < NN) deg[i] = 1.0f;   // self-loop
}

__global__ __launch_bounds__(256) void k_deg_scatter(const int* __restrict__ dst, float* __restrict__ deg) {
  int e = blockIdx.x * 256 + threadIdx.x;
  if (e < NE) unsafeAtomicAdd(&deg[dst[e]], 1.0f);
}

__global__ __launch_bounds__(256) void k_rsqrt(float* __restrict__ deg) {
  int i = blockIdx.x * 256 + threadIdx.x;
  if (i < NN) deg[i] = rsqrtf(deg[i]);   // deg >= 1 always
}

// ---------------- CSR build ----------------
// Exclusive scan of per-node in-edge counts (deg-1, pre-rsqrt). One block.
#define SCAN_T 1024
__global__ __launch_bounds__(SCAN_T) void k_scan(const float* __restrict__ deg,
                                                 int* __restrict__ row_off, int* __restrict__ cursor) {
  __shared__ int sums[SCAN_T];
  int t = threadIdx.x;
  const int CHUNK = (NN + SCAN_T - 1) / SCAN_T;   // 49
  int lo = t * CHUNK, hi = min(lo + CHUNK, NN);
  int s = 0;
  for (int i = lo; i < hi; ++i) s += (int)deg[i] - 1;
  sums[t] = s;
  __syncthreads();
  for (int off = 1; off < SCAN_T; off <<= 1) {
    int v = (t >= off) ? sums[t - off] : 0;
    __syncthreads();
    sums[t] += v;
    __syncthreads();
  }
  int run = (t > 0) ? sums[t - 1] : 0;   // exclusive base
  for (int i = lo; i < hi; ++i) {
    row_off[i] = run;
    cursor[i] = run;
    run += (int)deg[i] - 1;
  }
  if (t == SCAN_T - 1) row_off[NN] = run;
}

__global__ __launch_bounds__(256) void k_fill(const int* __restrict__ src, const int* __restrict__ dst,
                                              const float* __restrict__ dinv, int* __restrict__ cursor,
                                              int* __restrict__ csr_src, float* __restrict__ csr_nrm) {
  int e = blockIdx.x * 256 + threadIdx.x;
  if (e >= NE) return;
  int s = src[e], d = dst[e];
  int pos = atomicAdd(&cursor[d], 1);
  csr_src[pos] = s;
  csr_nrm[pos] = dinv[s] * dinv[d];
}

// ---------------- dense GEMM: out[r][c] = sum_k in[r][k] * W[c][k] ----------------
#define GEMM_ROWS 32
__global__ __launch_bounds__(256) void k_gemm(const float* __restrict__ in, const float* __restrict__ W,
                                              float* __restrict__ out) {
  __shared__ float wl[FD][FD + 1];
  __shared__ float xl[GEMM_ROWS][FD + 1];
  int t = threadIdx.x;
  int row0 = blockIdx.x * GEMM_ROWS;
  for (int i = t; i < FD * FD; i += 256) wl[i >> 7][i & 127] = W[i];
  for (int i = t; i < GEMM_ROWS * FD; i += 256) {
    int r = i >> 7, c = i & 127;
    int gr = row0 + r;
    xl[r][c] = (gr < NN) ? in[gr * FD + c] : 0.0f;
  }
  __syncthreads();
  int tr = (t >> 5) << 2;
  int tc = t & 31;
  float acc[4][4];
#pragma unroll
  for (int i = 0; i < 4; ++i)
#pragma unroll
    for (int j = 0; j < 4; ++j) acc[i][j] = 0.0f;

#pragma unroll 8
  for (int k = 0; k < FD; ++k) {
    float a0 = xl[tr + 0][k], a1 = xl[tr + 1][k], a2 = xl[tr + 2][k], a3 = xl[tr + 3][k];
    float b0 = wl[tc][k], b1 = wl[tc + 32][k], b2 = wl[tc + 64][k], b3 = wl[tc + 96][k];
    acc[0][0] = fmaf(a0, b0, acc[0][0]); acc[0][1] = fmaf(a0, b1, acc[0][1]);
    acc[0][2] = fmaf(a0, b2, acc[0][2]); acc[0][3] = fmaf(a0, b3, acc[0][3]);
    acc[1][0] = fmaf(a1, b0, acc[1][0]); acc[1][1] = fmaf(a1, b1, acc[1][1]);
    acc[1][2] = fmaf(a1, b2, acc[1][2]); acc[1][3] = fmaf(a1, b3, acc[1][3]);
    acc[2][0] = fmaf(a2, b0, acc[2][0]); acc[2][1] = fmaf(a2, b1, acc[2][1]);
    acc[2][2] = fmaf(a2, b2, acc[2][2]); acc[2][3] = fmaf(a2, b3, acc[2][3]);
    acc[3][0] = fmaf(a3, b0, acc[3][0]); acc[3][1] = fmaf(a3, b1, acc[3][1]);
    acc[3][2] = fmaf(a3, b2, acc[3][2]); acc[3][3] = fmaf(a3, b3, acc[3][3]);
  }
#pragma unroll
  for (int i = 0; i < 4; ++i) {
    int r = row0 + tr + i;
    if (r < NN) {
      out[r * FD + tc]      = acc[i][0];
      out[r * FD + tc + 32] = acc[i][1];
      out[r * FD + tc + 64] = acc[i][2];
      out[r * FD + tc + 96] = acc[i][3];
    }
  }
}

// ---------------- aggregation: gather form ----------------
// out[n] = bias + dinv[n]^2*h[n] + sum_{j in row(n)} csr_nrm[j]*h[csr_src[j]]
__global__ __launch_bounds__(256) void k_agg(const float* __restrict__ h, const float* __restrict__ dinv,
                                             const float* __restrict__ bias, const int* __restrict__ row_off,
                                             const int* __restrict__ csr_src, const float* __restrict__ csr_nrm,
                                             float* __restrict__ out) {
  int t = threadIdx.x;
  int n = blockIdx.x * 8 + (t >> 5);
  if (n >= NN) return;
  int q = t & 31;
  const float4* h4 = (const float4*)h;
  float dv = dinv[n];
  float s2 = dv * dv;
  float4 acc = ((const float4*)bias)[q];
  float4 hv = h4[n * 32 + q];
  acc.x = fmaf(s2, hv.x, acc.x);
  acc.y = fmaf(s2, hv.y, acc.y);
  acc.z = fmaf(s2, hv.z, acc.z);
  acc.w = fmaf(s2, hv.w, acc.w);
  int lo = row_off[n], hi = row_off[n + 1];
  for (int j = lo; j < hi; ++j) {
    int s = csr_src[j];
    float w = csr_nrm[j];
    float4 v = h4[s * 32 + q];
    acc.x = fmaf(w, v.x, acc.x);
    acc.y = fmaf(w, v.y, acc.y);
    acc.z = fmaf(w, v.z, acc.z);
    acc.w = fmaf(w, v.w, acc.w);
  }
  ((float4*)out)[n * 32 + q] = acc;
}

// ---------------- batchnorm ----------------
#define BN_BLOCKS 512
#define BN_RPB 98
__global__ __launch_bounds__(256) void k_bn_stats(const float* __restrict__ h, float* __restrict__ bnsum,
                                                  float* __restrict__ bnsq) {
  int t = threadIdx.x;
  int f = t & 127;
  int half = t >> 7;
  int r0 = blockIdx.x * BN_RPB + half;
  int r1 = min((int)(blockIdx.x + 1) * BN_RPB, NN);
  float s = 0.f, q = 0.f;
  for (int r = r0; r < r1; r += 2) {
    float v = h[r * FD + f];
    s += v;
    q += v * v;
  }
  unsafeAtomicAdd(&bnsum[f], s);
  unsafeAtomicAdd(&bnsq[f], q);
}

__global__ __launch_bounds__(128) void k_bn_final(const float* __restrict__ bnsum, const float* __restrict__ bnsq,
                                                  float* __restrict__ mu, float* __restrict__ scale) {
  int f = threadIdx.x;
  if (f < FD) {
    float m = bnsum[f] * (1.0f / NN);
    float v = bnsq[f] * (1.0f / NN) - m * m;
    v = fmaxf(v, 0.0f);
    mu[f] = m;
    scale[f] = rsqrtf(v + EPS_BN);
  }
}

__global__ __launch_bounds__(256) void k_bn_apply(float* __restrict__ h, const float* __restrict__ mu,
                                                  const float* __restrict__ scale) {
  int i = blockIdx.x * 256 + threadIdx.x;
  if (i >= NN * FD / 4) return;
  int q = i & 31;
  float4 v = ((float4*)h)[i];
  float4 m = ((const float4*)mu)[q];
  float4 sc = ((const float4*)scale)[q];
  v.x = fmaxf((v.x - m.x) * sc.x, 0.0f);
  v.y = fmaxf((v.y - m.y) * sc.y, 0.0f);
  v.z = fmaxf((v.z - m.z) * sc.z, 0.0f);
  v.w = fmaxf((v.w - m.w) * sc.w, 0.0f);
  ((float4*)h)[i] = v;
}

// ---------------- pooling + head (segmented: batch is sorted) ----------------
__global__ __launch_bounds__(128) void k_gstart(const int* __restrict__ batch, int* __restrict__ gstart) {
  int g = blockIdx.x * 128 + threadIdx.x;
  if (g > NG) return;
  int lo = 0, hi = NN;   // first index with batch[i] >= g
  while (lo < hi) {
    int mid = (lo + hi) >> 1;
    if (batch[mid] < g) lo = mid + 1; else hi = mid;
  }
  gstart[g] = lo;
}

__global__ __launch_bounds__(128) void k_pool(const float* __restrict__ h, const int* __restrict__ gstart,
                                              float* __restrict__ pooled) {
  int g = blockIdx.x, f = threadIdx.x;
  int lo = gstart[g], hi = gstart[g + 1];
  float s = 0.f;
  for (int n = lo; n < hi; ++n) s += h[n * FD + f];
  float ic = 1.0f / fmaxf((float)(hi - lo), 1.0f);
  pooled[g * FD + f] = s * ic;
}

__global__ __launch_bounds__(128) void k_final(const float* __restrict__ pooled,
                                               const float* __restrict__ Wlin, const float* __restrict__ blin,
                                               float* __restrict__ out) {
  __shared__ float p[FD];
  int g = blockIdx.x, t = threadIdx.x;
  p[t] = pooled[g * FD + t];
  __syncthreads();
  if (t < NC) {
    float a = blin[t];
    for (int k = 0; k < FD; ++k) a = fmaf(p[k], Wlin[t * FD + k], a);
    out[g * NC + t] = a;
  }
}

// ---------------- launch ----------------
extern "C" void kernel_launch(void* const* d_in, const int* in_sizes, int n_in,
                              void* d_out, int out_size, void* d_ws, size_t ws_size,
                              hipStream_t stream) {
  const float* x    = (const float*)d_in[0];
  const int*   ei   = (const int*)d_in[1];
  const int*   batch= (const int*)d_in[2];
  const float* W1   = (const float*)d_in[3];
  const float* b1   = (const float*)d_in[4];
  const float* W2   = (const float*)d_in[5];
  const float* b2   = (const float*)d_in[6];
  const float* W3   = (const float*)d_in[7];
  const float* b3   = (const float*)d_in[8];
  const float* Wlin = (const float*)d_in[9];
  const float* blin = (const float*)d_in[10];
  float* out = (float*)d_out;
  float* ws  = (float*)d_ws;

  const int* srcI = ei;
  const int* dstI = ei + NE;

  float* deg    = ws;                     // NN (dinv after k_rsqrt)
  float* bufA   = ws + 50048;             // NN*FD
  float* bufB   = bufA + NN * FD;         // NN*FD
  float* bnsum  = bufB + NN * FD;         // FD
  float* bnsq   = bnsum + FD;             // FD
  float* mu     = bnsq + FD;              // FD
  float* scale  = mu + FD;                // FD
  float* pooled = scale + FD;             // NG*FD
  float* csr_nrm= pooled + NG * FD;       // NE
  int*   csr_src= (int*)(csr_nrm + NE);   // NE
  int*   row_off= csr_src + NE;           // NN+1
  int*   cursor = row_off + 50048;        // NN
  int*   gstart = cursor + 50048;         // NG+1

  dim3 B(256);
  const int gN    = (NN + 255) / 256;
  const int gE    = (NE + 255) / 256;
  const int gGemm = (NN + GEMM_ROWS - 1) / GEMM_ROWS;
  const int gEl4  = (NN * FD / 4 + 255) / 256;
  const int gAgg  = NN / 8;   // 6250, exact

  // degree -> CSR -> dinv
  k_init_deg<<<gN, B, 0, stream>>>(deg);
  k_deg_scatter<<<gE, B, 0, stream>>>(dstI, deg);
  k_scan<<<1, SCAN_T, 0, stream>>>(deg, row_off, cursor);
  k_rsqrt<<<gN, B, 0, stream>>>(deg);
  k_fill<<<gE, B, 0, stream>>>(srcI, dstI, deg, cursor, csr_src, csr_nrm);
  k_gstart<<<5, 128, 0, stream>>>(batch, gstart);

  // layer 1
  k_gemm<<<gGemm, B, 0, stream>>>(x, W1, bufA);
  k_agg<<<gAgg, B, 0, stream>>>(bufA, deg, b1, row_off, csr_src, csr_nrm, bufB);
  hipMemsetAsync(bnsum, 0, 2 * FD * sizeof(float), stream);
  k_bn_stats<<<BN_BLOCKS, B, 0, stream>>>(bufB, bnsum, bnsq);
  k_bn_final<<<1, 128, 0, stream>>>(bnsum, bnsq, mu, scale);
  k_bn_apply<<<gEl4, B, 0, stream>>>(bufB, mu, scale);

  // layer 2
  k_gemm<<<gGemm, B, 0, stream>>>(bufB, W2, bufA);
  k_agg<<<gAgg, B, 0, stream>>>(bufA, deg, b2, row_off, csr_src, csr_nrm, bufB);
  hipMemsetAsync(bnsum, 0, 2 * FD * sizeof(float), stream);
  k_bn_stats<<<BN_BLOCKS, B, 0, stream>>>(bufB, bnsum, bnsq);
  k_bn_final<<<1, 128, 0, stream>>>(bnsum, bnsq, mu, scale);
  k_bn_apply<<<gEl4, B, 0, stream>>>(bufB, mu, scale);

  // layer 3 (no BN/ReLU)
  k_gemm<<<gGemm, B, 0, stream>>>(bufB, W3, bufA);
  k_agg<<<gAgg, B, 0, stream>>>(bufA, deg, b3, row_off, csr_src, csr_nrm, bufB);

  // pool + head
  k_pool<<<NG, 128, 0, stream>>>(bufB, gstart, pooled);
  k_final<<<NG, 128, 0, stream>>>(pooled, Wlin, blin, out);
}

// Round 3
// 499.419 us; speedup vs baseline: 7.2203x; 1.4982x over previous
//
#include <hip/hip_runtime.h>
#include <hip/hip_bf16.h>

#define NN 50000
#define NE 600000
#define FD 128
#define NG 512
#define NC 10
static constexpr float EPS_BN = 1e-5f;

typedef __bf16 bf16x8 __attribute__((ext_vector_type(8)));
typedef float f32x4 __attribute__((ext_vector_type(4)));

__device__ __forceinline__ unsigned short f2bf(float x) {
  unsigned u = __float_as_uint(x);
  u = (u + 0x7FFFu + ((u >> 16) & 1u)) >> 16;
  return (unsigned short)u;
}
__device__ __forceinline__ float bf2f(unsigned short h) {
  return __uint_as_float(((unsigned)h) << 16);
}

// ---------------- degree / norm ----------------
__global__ __launch_bounds__(256) void k_init_deg(float* __restrict__ deg) {
  int i = blockIdx.x * 256 + threadIdx.x;
  if (i < NN) deg[i] = 1.0f;   // self-loop
}

__global__ __launch_bounds__(256) void k_deg_scatter(const int* __restrict__ dst, float* __restrict__ deg) {
  int e = blockIdx.x * 256 + threadIdx.x;
  if (e < NE) unsafeAtomicAdd(&deg[dst[e]], 1.0f);
}

__global__ __launch_bounds__(256) void k_rsqrt(float* __restrict__ deg) {
  int i = blockIdx.x * 256 + threadIdx.x;
  if (i < NN) deg[i] = rsqrtf(deg[i]);   // deg >= 1 always
}

// ---------------- CSR build: multi-block exclusive scan of (deg-1) ----------------
#define NB 196   // ceil(50000/256)
__global__ __launch_bounds__(256) void k_bsum(const float* __restrict__ deg, int* __restrict__ bsum) {
  __shared__ int s[256];
  int t = threadIdx.x, i = blockIdx.x * 256 + t;
  s[t] = (i < NN) ? (int)deg[i] - 1 : 0;
  __syncthreads();
  for (int o = 128; o > 0; o >>= 1) { if (t < o) s[t] += s[t + o]; __syncthreads(); }
  if (t == 0) bsum[blockIdx.x] = s[0];
}

__global__ __launch_bounds__(256) void k_bscan(const int* __restrict__ bsum, int* __restrict__ bbase) {
  __shared__ int s[256];
  int t = threadIdx.x;
  int v = (t < NB) ? bsum[t] : 0;
  s[t] = v; __syncthreads();
  for (int o = 1; o < 256; o <<= 1) {
    int a = (t >= o) ? s[t - o] : 0; __syncthreads();
    s[t] += a; __syncthreads();
  }
  if (t < NB) bbase[t] = s[t] - v;
}

__global__ __launch_bounds__(256) void k_rowoff(const float* __restrict__ deg, const int* __restrict__ bbase,
                                                int* __restrict__ row_off, int* __restrict__ cursor) {
  __shared__ int s[256];
  int t = threadIdx.x, i = blockIdx.x * 256 + t;
  int c = (i < NN) ? (int)deg[i] - 1 : 0;
  s[t] = c; __syncthreads();
  for (int o = 1; o < 256; o <<= 1) {
    int a = (t >= o) ? s[t - o] : 0; __syncthreads();
    s[t] += a; __syncthreads();
  }
  int excl = s[t] - c + bbase[blockIdx.x];
  if (i <= NN) {
    row_off[i] = excl;
    if (i < NN) cursor[i] = excl;
  }
}

__global__ __launch_bounds__(256) void k_fill(const int* __restrict__ src, const int* __restrict__ dst,
                                              const float* __restrict__ dinv, int* __restrict__ cursor,
                                              int* __restrict__ csr_src, float* __restrict__ csr_nrm) {
  int e = blockIdx.x * 256 + threadIdx.x;
  if (e >= NE) return;
  int s = src[e], d = dst[e];
  int pos = atomicAdd(&cursor[d], 1);
  csr_src[pos] = s;
  csr_nrm[pos] = dinv[s] * dinv[d];
}

// ---------------- conversions fp32 -> bf16 hi/lo ----------------
__device__ __forceinline__ void cvt4(float4 v, ushort4* hp, ushort4* lp) {
  ushort4 hv, lv;
  hv.x = f2bf(v.x); lv.x = f2bf(v.x - bf2f(hv.x));
  hv.y = f2bf(v.y); lv.y = f2bf(v.y - bf2f(hv.y));
  hv.z = f2bf(v.z); lv.z = f2bf(v.z - bf2f(hv.z));
  hv.w = f2bf(v.w); lv.w = f2bf(v.w - bf2f(hv.w));
  *hp = hv; *lp = lv;
}

__global__ __launch_bounds__(256) void k_cvt_x(const float* __restrict__ x,
                                               unsigned short* __restrict__ xhi, unsigned short* __restrict__ xlo) {
  int i = blockIdx.x * 256 + threadIdx.x;
  if (i >= NN * FD / 4) return;
  float4 v = ((const float4*)x)[i];
  ushort4 hv, lv; cvt4(v, &hv, &lv);
  ((ushort4*)xhi)[i] = hv;
  ((ushort4*)xlo)[i] = lv;
}

__global__ __launch_bounds__(256) void k_cvt_w(const float* __restrict__ W1, const float* __restrict__ W2,
                                               const float* __restrict__ W3,
                                               unsigned short* __restrict__ whi, unsigned short* __restrict__ wlo) {
  int m = blockIdx.y;
  const float* W = (m == 0) ? W1 : ((m == 1) ? W2 : W3);
  int i = blockIdx.x * 256 + threadIdx.x;
  if (i >= FD * FD / 4) return;
  float4 v = ((const float4*)W)[i];
  ushort4 hv, lv; cvt4(v, &hv, &lv);
  ((ushort4*)(whi + m * FD * FD))[i] = hv;
  ((ushort4*)(wlo + m * FD * FD))[i] = lv;
}

// ---------------- MFMA GEMM: out[r][c] = sum_k in[r][k] * W[c][k] ----------------
// split-bf16: in = ih + il, W = wh + wl; out = ih*wh + ih*wl + il*wh (fp32 acc)
// No LDS: 16x16x32 fragments are contiguous 16B runs of the row-major operands.
__global__ __launch_bounds__(256) void k_gemm(const unsigned short* __restrict__ xhi,
                                              const unsigned short* __restrict__ xlo,
                                              const unsigned short* __restrict__ whi,
                                              const unsigned short* __restrict__ wlo,
                                              float* __restrict__ out) {
  int t = threadIdx.x;
  int w = t >> 6, l = t & 63;
  int rt = blockIdx.x * 4 + w;               // row-tile (16 rows), 3125 total
  if (rt >= NN / 16) return;
  int row0 = rt * 16;
  int r = l & 15, g = l >> 4;                // r: A-row / B-col, g: k-group
  int ko = g * 8;
  f32x4 acc[8];
#pragma unroll
  for (int ct = 0; ct < 8; ++ct) acc[ct] = (f32x4){0.f, 0.f, 0.f, 0.f};

#pragma unroll
  for (int kk = 0; kk < FD; kk += 32) {
    bf16x8 ah = *(const bf16x8*)(xhi + (size_t)(row0 + r) * FD + kk + ko);
    bf16x8 al = *(const bf16x8*)(xlo + (size_t)(row0 + r) * FD + kk + ko);
#pragma unroll
    for (int ct = 0; ct < 8; ++ct) {
      bf16x8 bh = *(const bf16x8*)(whi + (size_t)(ct * 16 + r) * FD + kk + ko);
      bf16x8 bl = *(const bf16x8*)(wlo + (size_t)(ct * 16 + r) * FD + kk + ko);
      acc[ct] = __builtin_amdgcn_mfma_f32_16x16x32_bf16(ah, bh, acc[ct], 0, 0, 0);
      acc[ct] = __builtin_amdgcn_mfma_f32_16x16x32_bf16(ah, bl, acc[ct], 0, 0, 0);
      acc[ct] = __builtin_amdgcn_mfma_f32_16x16x32_bf16(al, bh, acc[ct], 0, 0, 0);
    }
  }
  // C/D layout: col = lane&15 (=r), row = g*4 + reg
#pragma unroll
  for (int ct = 0; ct < 8; ++ct)
#pragma unroll
    for (int i = 0; i < 4; ++i)
      out[(size_t)(row0 + g * 4 + i) * FD + ct * 16 + r] = acc[ct][i];
}

// ---------------- aggregation: gather form ----------------
__global__ __launch_bounds__(256) void k_agg(const float* __restrict__ h, const float* __restrict__ dinv,
                                             const float* __restrict__ bias, const int* __restrict__ row_off,
                                             const int* __restrict__ csr_src, const float* __restrict__ csr_nrm,
                                             float* __restrict__ out) {
  int t = threadIdx.x;
  int n = blockIdx.x * 8 + (t >> 5);
  if (n >= NN) return;
  int q = t & 31;
  const float4* h4 = (const float4*)h;
  float dv = dinv[n];
  float s2 = dv * dv;
  float4 acc = ((const float4*)bias)[q];
  float4 hv = h4[n * 32 + q];
  acc.x = fmaf(s2, hv.x, acc.x);
  acc.y = fmaf(s2, hv.y, acc.y);
  acc.z = fmaf(s2, hv.z, acc.z);
  acc.w = fmaf(s2, hv.w, acc.w);
  int lo = row_off[n], hi = row_off[n + 1];
  for (int j = lo; j < hi; ++j) {
    int s = csr_src[j];
    float w = csr_nrm[j];
    float4 v = h4[s * 32 + q];
    acc.x = fmaf(w, v.x, acc.x);
    acc.y = fmaf(w, v.y, acc.y);
    acc.z = fmaf(w, v.z, acc.z);
    acc.w = fmaf(w, v.w, acc.w);
  }
  ((float4*)out)[n * 32 + q] = acc;
}

// ---------------- batchnorm ----------------
#define BN_BLOCKS 512
#define BN_RPB 98
__global__ __launch_bounds__(256) void k_bn_stats(const float* __restrict__ h, float* __restrict__ bnsum,
                                                  float* __restrict__ bnsq) {
  int t = threadIdx.x;
  int f = t & 127;
  int half = t >> 7;
  int r0 = blockIdx.x * BN_RPB + half;
  int r1 = min((int)(blockIdx.x + 1) * BN_RPB, NN);
  float s = 0.f, q = 0.f;
  for (int r = r0; r < r1; r += 2) {
    float v = h[r * FD + f];
    s += v;
    q += v * v;
  }
  unsafeAtomicAdd(&bnsum[f], s);
  unsafeAtomicAdd(&bnsq[f], q);
}

// BN normalize + ReLU, emit bf16 hi/lo for the next GEMM (mu/scale computed inline)
__global__ __launch_bounds__(256) void k_bn_apply_cvt(const float* __restrict__ h,
                                                      const float* __restrict__ bnsum, const float* __restrict__ bnsq,
                                                      unsigned short* __restrict__ xhi, unsigned short* __restrict__ xlo) {
  int i = blockIdx.x * 256 + threadIdx.x;
  if (i >= NN * FD / 4) return;
  int q = i & 31;
  float4 v = ((const float4*)h)[i];
  float4 sm = ((const float4*)bnsum)[q];
  float4 sq = ((const float4*)bnsq)[q];
  const float inv = 1.0f / NN;
  float4 o;
  {
    float m = sm.x * inv, va = fmaxf(sq.x * inv - m * m, 0.f), sc = rsqrtf(va + EPS_BN);
    o.x = fmaxf((v.x - m) * sc, 0.f);
    m = sm.y * inv; va = fmaxf(sq.y * inv - m * m, 0.f); sc = rsqrtf(va + EPS_BN);
    o.y = fmaxf((v.y - m) * sc, 0.f);
    m = sm.z * inv; va = fmaxf(sq.z * inv - m * m, 0.f); sc = rsqrtf(va + EPS_BN);
    o.z = fmaxf((v.z - m) * sc, 0.f);
    m = sm.w * inv; va = fmaxf(sq.w * inv - m * m, 0.f); sc = rsqrtf(va + EPS_BN);
    o.w = fmaxf((v.w - m) * sc, 0.f);
  }
  ushort4 hv, lv; cvt4(o, &hv, &lv);
  ((ushort4*)xhi)[i] = hv;
  ((ushort4*)xlo)[i] = lv;
}

// ---------------- pooling + head (segmented: batch is sorted) ----------------
__global__ __launch_bounds__(128) void k_gstart(const int* __restrict__ batch, int* __restrict__ gstart) {
  int g = blockIdx.x * 128 + threadIdx.x;
  if (g > NG) return;
  int lo = 0, hi = NN;
  while (lo < hi) {
    int mid = (lo + hi) >> 1;
    if (batch[mid] < g) lo = mid + 1; else hi = mid;
  }
  gstart[g] = lo;
}

__global__ __launch_bounds__(128) void k_pool(const float* __restrict__ h, const int* __restrict__ gstart,
                                              float* __restrict__ pooled) {
  int g = blockIdx.x, f = threadIdx.x;
  int lo = gstart[g], hi = gstart[g + 1];
  float s = 0.f;
  for (int n = lo; n < hi; ++n) s += h[n * FD + f];
  float ic = 1.0f / fmaxf((float)(hi - lo), 1.0f);
  pooled[g * FD + f] = s * ic;
}

__global__ __launch_bounds__(128) void k_final(const float* __restrict__ pooled,
                                               const float* __restrict__ Wlin, const float* __restrict__ blin,
                                               float* __restrict__ out) {
  __shared__ float p[FD];
  int g = blockIdx.x, t = threadIdx.x;
  p[t] = pooled[g * FD + t];
  __syncthreads();
  if (t < NC) {
    float a = blin[t];
    for (int k = 0; k < FD; ++k) a = fmaf(p[k], Wlin[t * FD + k], a);
    out[g * NC + t] = a;
  }
}

// ---------------- launch ----------------
extern "C" void kernel_launch(void* const* d_in, const int* in_sizes, int n_in,
                              void* d_out, int out_size, void* d_ws, size_t ws_size,
                              hipStream_t stream) {
  const float* x    = (const float*)d_in[0];
  const int*   ei   = (const int*)d_in[1];
  const int*   batch= (const int*)d_in[2];
  const float* W1   = (const float*)d_in[3];
  const float* b1   = (const float*)d_in[4];
  const float* W2   = (const float*)d_in[5];
  const float* b2   = (const float*)d_in[6];
  const float* W3   = (const float*)d_in[7];
  const float* b3   = (const float*)d_in[8];
  const float* Wlin = (const float*)d_in[9];
  const float* blin = (const float*)d_in[10];
  float* out = (float*)d_out;
  float* ws  = (float*)d_ws;

  const int* srcI = ei;
  const int* dstI = ei + NE;

  float* deg    = ws;                      // NN (dinv after k_rsqrt)
  float* bufA   = ws + 50048;              // NN*FD
  float* bufB   = bufA + NN * FD;          // NN*FD
  float* bnsum  = bufB + NN * FD;          // FD
  float* bnsq   = bnsum + FD;              // FD
  float* pooled = bnsq + FD;               // NG*FD
  float* csr_nrm= pooled + NG * FD;        // NE
  int*   csr_src= (int*)(csr_nrm + NE);    // NE
  int*   row_off= csr_src + NE;            // NN+1
  int*   cursor = row_off + 50048;         // NN
  int*   gstart = cursor + 50048;          // NG+1 (pad 1024)
  int*   bsum   = gstart + 1024;           // NB (pad 256)
  int*   bbase  = bsum + 256;              // NB (pad 256)
  unsigned short* xhi = (unsigned short*)(bbase + 256);  // NN*FD
  unsigned short* xlo = xhi + NN * FD;                    // NN*FD
  unsigned short* whi = xlo + NN * FD;                    // 3*FD*FD
  unsigned short* wlo = whi + 3 * FD * FD;                // 3*FD*FD

  dim3 B(256);
  const int gN    = (NN + 255) / 256;
  const int gE    = (NE + 255) / 256;
  const int gGemm = (NN / 16 + 3) / 4;     // 782 blocks, 4 row-tiles each
  const int gEl4  = (NN * FD / 4 + 255) / 256;
  const int gAgg  = NN / 8;

  // degree -> CSR -> dinv
  k_init_deg<<<gN, B, 0, stream>>>(deg);
  k_deg_scatter<<<gE, B, 0, stream>>>(dstI, deg);
  k_bsum<<<NB, B, 0, stream>>>(deg, bsum);
  k_bscan<<<1, B, 0, stream>>>(bsum, bbase);
  k_rowoff<<<NB, B, 0, stream>>>(deg, bbase, row_off, cursor);
  k_rsqrt<<<gN, B, 0, stream>>>(deg);
  k_fill<<<gE, B, 0, stream>>>(srcI, dstI, deg, cursor, csr_src, csr_nrm);
  k_gstart<<<5, 128, 0, stream>>>(batch, gstart);
  k_cvt_w<<<dim3(16, 3), B, 0, stream>>>(W1, W2, W3, whi, wlo);
  k_cvt_x<<<gEl4, B, 0, stream>>>(x, xhi, xlo);

  // layer 1
  k_gemm<<<gGemm, B, 0, stream>>>(xhi, xlo, whi, wlo, bufA);
  k_agg<<<gAgg, B, 0, stream>>>(bufA, deg, b1, row_off, csr_src, csr_nrm, bufB);
  hipMemsetAsync(bnsum, 0, 2 * FD * sizeof(float), stream);
  k_bn_stats<<<BN_BLOCKS, B, 0, stream>>>(bufB, bnsum, bnsq);
  k_bn_apply_cvt<<<gEl4, B, 0, stream>>>(bufB, bnsum, bnsq, xhi, xlo);

  // layer 2
  k_gemm<<<gGemm, B, 0, stream>>>(xhi, xlo, whi + FD * FD, wlo + FD * FD, bufA);
  k_agg<<<gAgg, B, 0, stream>>>(bufA, deg, b2, row_off, csr_src, csr_nrm, bufB);
  hipMemsetAsync(bnsum, 0, 2 * FD * sizeof(float), stream);
  k_bn_stats<<<BN_BLOCKS, B, 0, stream>>>(bufB, bnsum, bnsq);
  k_bn_apply_cvt<<<gEl4, B, 0, stream>>>(bufB, bnsum, bnsq, xhi, xlo);

  // layer 3 (no BN/ReLU)
  k_gemm<<<gGemm, B, 0, stream>>>(xhi, xlo, whi + 2 * FD * FD, wlo + 2 * FD * FD, bufA);
  k_agg<<<gAgg, B, 0, stream>>>(bufA, deg, b3, row_off, csr_src, csr_nrm, bufB);

  // pool + head
  k_pool<<<NG, 128, 0, stream>>>(bufB, gstart, pooled);
  k_final<<<NG, 128, 0, stream>>>(pooled, Wlin, blin, out);
}